// Round 1
// baseline (179.027 us; speedup 1.0000x reference)
//
#include <hip/hip_runtime.h>
#include <math.h>

// Problem shape (fixed by setup_inputs)
#define BATCH 32
#define HH 768
#define WW 768
#define RS 96            // level-3 region side (768/8)
#define NREG 64          // 8x8 regions
#define NBLK (BATCH * NREG)  // 2048 region blocks

// ---------------------------------------------------------------------------
// Kernel 1: one block per (batch, region). Computes region sum of pred, gt,
// and sum of squared diff. Fully coalesced float4 loads (region base is a
// multiple of 384 bytes; row stride 768 floats keeps 16B alignment).
// ---------------------------------------------------------------------------
__global__ __launch_bounds__(256) void region_reduce(
    const float* __restrict__ pred, const float* __restrict__ gt,
    float* __restrict__ sq_out, float* __restrict__ sp_out,
    float* __restrict__ sg_out)
{
    const int bid = blockIdx.x;          // b*64 + r
    const int b  = bid >> 6;
    const int r  = bid & 63;
    const int ri = r >> 3, rj = r & 7;
    const size_t base = (size_t)b * (HH * WW) + (size_t)ri * RS * WW + (size_t)rj * RS;
    const float* __restrict__ pb = pred + base;
    const float* __restrict__ gb = gt + base;

    float sp = 0.f, sg = 0.f, sq = 0.f;
    // region = 96 rows x 24 float4 per row = 2304 float4 pairs; 9/thread
    for (int q = threadIdx.x; q < RS * 24; q += 256) {
        const int row = q / 24;
        const int c4  = q - row * 24;
        const float4 p = *(const float4*)(pb + (size_t)row * WW + c4 * 4);
        const float4 g = *(const float4*)(gb + (size_t)row * WW + c4 * 4);
        sp += (p.x + p.y) + (p.z + p.w);
        sg += (g.x + g.y) + (g.z + g.w);
        const float dx = p.x - g.x, dy = p.y - g.y;
        const float dz = p.z - g.z, dw = p.w - g.w;
        sq += (dx * dx + dy * dy) + (dz * dz + dw * dw);
    }

    // wave(64)-level shuffle reduction, then across the 4 waves via LDS
    #pragma unroll
    for (int off = 32; off > 0; off >>= 1) {
        sp += __shfl_down(sp, off, 64);
        sg += __shfl_down(sg, off, 64);
        sq += __shfl_down(sq, off, 64);
    }
    __shared__ float lsp[4], lsg[4], lsq[4];
    const int wave = threadIdx.x >> 6;
    const int lane = threadIdx.x & 63;
    if (lane == 0) { lsp[wave] = sp; lsg[wave] = sg; lsq[wave] = sq; }
    __syncthreads();
    if (threadIdx.x == 0) {
        sp_out[bid] = (lsp[0] + lsp[1]) + (lsp[2] + lsp[3]);
        sg_out[bid] = (lsg[0] + lsg[1]) + (lsg[2] + lsg[3]);
        sq_out[bid] = (lsq[0] + lsq[1]) + (lsq[2] + lsq[3]);
    }
}

// ---------------------------------------------------------------------------
// Kernel 2: single block. Combines everything into the scalar loss.
// ---------------------------------------------------------------------------
__device__ inline float block_sum(float v, float* red, int t) {
    red[t] = v;
    __syncthreads();
    #pragma unroll
    for (int off = 128; off > 0; off >>= 1) {
        if (t < off) red[t] += red[t + off];
        __syncthreads();
    }
    const float r = red[0];
    __syncthreads();
    return r;
}

__global__ __launch_bounds__(256) void finalize(
    const float* __restrict__ sq, const float* __restrict__ sp,
    const float* __restrict__ sg, const float* __restrict__ rgb,
    const float* __restrict__ th, float* __restrict__ out)
{
    __shared__ float d[NBLK];        // level-3 region diffs, 8 KB
    __shared__ float d2[BATCH * 16]; // level-2 diffs
    __shared__ float d1[BATCH * 4];  // level-1 diffs
    __shared__ float red[256];
    const int t = threadIdx.x;

    // density partial sum + level-3 diffs
    float s_sq = 0.f;
    float l3 = 0.f;
    for (int i = t; i < NBLK; i += 256) {
        s_sq += sq[i];
        const float v = sp[i] - sg[i];
        d[i] = v;
        l3 += fabsf(v);
    }
    __syncthreads();

    // level 2: 32 batches x 16 regions = 512 aggregates of 2x2 level-3 cells
    float l2 = 0.f;
    for (int i = t; i < BATCH * 16; i += 256) {
        const int b = i >> 4, r2 = i & 15;
        const int i2 = r2 >> 2, j2 = r2 & 3;
        const float* db = d + b * 64;
        const float v = (db[(2 * i2) * 8 + 2 * j2]     + db[(2 * i2) * 8 + 2 * j2 + 1])
                      + (db[(2 * i2 + 1) * 8 + 2 * j2] + db[(2 * i2 + 1) * 8 + 2 * j2 + 1]);
        d2[i] = v;
        l2 += fabsf(v);
    }
    __syncthreads();

    // level 1: 32 x 4 aggregates of 2x2 level-2 cells
    float l1 = 0.f;
    if (t < BATCH * 4) {
        const int b = t >> 2, r1 = t & 3;
        const int i1 = r1 >> 1, j1 = r1 & 1;
        const float* db = d2 + b * 16;
        const float v = (db[(2 * i1) * 4 + 2 * j1]     + db[(2 * i1) * 4 + 2 * j1 + 1])
                      + (db[(2 * i1 + 1) * 4 + 2 * j1] + db[(2 * i1 + 1) * 4 + 2 * j1 + 1]);
        d1[t] = v;
        l1 = fabsf(v);
    }
    __syncthreads();

    // per-batch count diff (= sum of the 4 level-1 diffs) + domain CE
    float cnt = 0.f, dom = 0.f;
    if (t < BATCH) {
        const float c = (d1[t * 4] + d1[t * 4 + 1]) + (d1[t * 4 + 2] + d1[t * 4 + 3]);
        cnt = fabsf(c);
        // CE, label 0 for rgb: lse - x0 ; label 1 for thermal: lse - y1
        const float x0 = rgb[t * 2], x1 = rgb[t * 2 + 1];
        const float mx = fmaxf(x0, x1);
        dom  = (mx + logf(expf(x0 - mx) + expf(x1 - mx))) - x0;
        const float y0 = th[t * 2], y1 = th[t * 2 + 1];
        const float my = fmaxf(y0, y1);
        dom += (my + logf(expf(y0 - my) + expf(y1 - my))) - y1;
    }

    const float S_sq  = block_sum(s_sq, red, t);
    const float S_l3  = block_sum(l3, red, t);
    const float S_l2  = block_sum(l2, red, t);
    const float S_l1  = block_sum(l1, red, t);
    const float S_cnt = block_sum(cnt, red, t);
    const float S_dom = block_sum(dom, red, t);

    if (t == 0) {
        const float density = S_sq / (float)((size_t)BATCH * HH * WW);
        const float count_l = S_cnt / (float)BATCH;
        // regional: each level is mean over batch (/32), sum over regions;
        // total / (3 levels * 8 * 8)
        const float regional = ((S_l1 + S_l2 + S_l3) / (float)BATCH) / 192.0f;
        // domain: (mean_b ce_rgb + mean_b ce_th)/2 = S_dom / 64
        const float domain = S_dom / 64.0f;
        out[0] = 100.0f * density + 0.001f * count_l + 1.0f * regional
               + 0.5f * domain;
    }
}

extern "C" void kernel_launch(void* const* d_in, const int* in_sizes, int n_in,
                              void* d_out, int out_size, void* d_ws, size_t ws_size,
                              hipStream_t stream) {
    const float* pred = (const float*)d_in[0];
    const float* gt   = (const float*)d_in[1];
    const float* rgb  = (const float*)d_in[2];
    const float* th   = (const float*)d_in[3];
    float* out = (float*)d_out;

    float* sq = (float*)d_ws;          // [2048]
    float* sp = sq + NBLK;             // [2048]
    float* sg = sp + NBLK;             // [2048]

    region_reduce<<<NBLK, 256, 0, stream>>>(pred, gt, sq, sp, sg);
    finalize<<<1, 256, 0, stream>>>(sq, sp, sg, rgb, th, out);
}

// Round 2
// 171.701 us; speedup vs baseline: 1.0427x; 1.0427x over previous
//
#include <hip/hip_runtime.h>
#include <math.h>

// Problem shape (fixed by setup_inputs)
#define BATCH 32
#define HH 768
#define WW 768
#define NREG 64              // 8x8 level-3 regions
#define NBLK (BATCH * NREG)  // 2048 blocks
// Block = (b, ri, chunk): 12 full-width rows. 8 chunks cover one region-row band.
// Thread group g = t>>5 (32 lanes) owns rj-stripe g (cols [96g, 96g+96)).

// ---------------------------------------------------------------------------
// Kernel 1: contiguous reads, all 18 float4 loads in flight per thread.
// Outputs: sq partial per block [2048], and d (sum pred - sum gt) per
// (region, chunk): dws[region*8 + chunk], region = b*64 + ri*8 + rj.
// ---------------------------------------------------------------------------
__global__ __launch_bounds__(256) void region_reduce(
    const float* __restrict__ pred, const float* __restrict__ gt,
    float* __restrict__ sq_out, float* __restrict__ dws)
{
    const int bid   = blockIdx.x;        // b*64 + ri*8 + chunk
    const int b     = bid >> 6;
    const int ri    = (bid >> 3) & 7;
    const int chunk = bid & 7;
    const size_t base = (size_t)b * (HH * WW) + (size_t)(ri * 96 + chunk * 12) * WW;

    const int t = threadIdx.x;
    const int g = t >> 5;       // rj stripe 0..7
    const int l = t & 31;

    const float* __restrict__ pb = pred + base + g * 96;
    const float* __restrict__ gb = gt   + base + g * 96;

    // stripe = 12 rows x 24 float4; lane l handles q = l + 32k, k=0..8
    int offs[9];
    #pragma unroll
    for (int k = 0; k < 9; ++k) {
        const int q   = l + 32 * k;      // 0..287
        const int row = q / 24;
        const int c   = q - row * 24;
        offs[k] = row * WW + c * 4;
    }
    float4 p[9], q4[9];
    #pragma unroll
    for (int k = 0; k < 9; ++k) p[k]  = *(const float4*)(pb + offs[k]);
    #pragma unroll
    for (int k = 0; k < 9; ++k) q4[k] = *(const float4*)(gb + offs[k]);

    float sq = 0.f, ds = 0.f;
    #pragma unroll
    for (int k = 0; k < 9; ++k) {
        const float dx = p[k].x - q4[k].x;
        const float dy = p[k].y - q4[k].y;
        const float dz = p[k].z - q4[k].z;
        const float dw = p[k].w - q4[k].w;
        sq += (dx * dx + dy * dy) + (dz * dz + dw * dw);
        ds += (dx + dy) + (dz + dw);
    }

    // ds: reduce within the 32-lane group (offsets stay inside the group)
    #pragma unroll
    for (int off = 16; off > 0; off >>= 1) ds += __shfl_down(ds, off, 64);
    // sq: reduce across the full 64-lane wave
    #pragma unroll
    for (int off = 32; off > 0; off >>= 1) sq += __shfl_down(sq, off, 64);

    if (l == 0) dws[((((b << 3) + ri) << 3) + g) * 8 + chunk] = ds;

    __shared__ float lsq[4];
    const int wave = t >> 6;
    if ((t & 63) == 0) lsq[wave] = sq;
    __syncthreads();
    if (t == 0) sq_out[bid] = (lsq[0] + lsq[1]) + (lsq[2] + lsq[3]);
}

// ---------------------------------------------------------------------------
// Kernel 2: single block. Aggregates chunk partials -> level-3 regions,
// builds levels 2/1, count loss, domain CE, final weighted sum.
// ---------------------------------------------------------------------------
__global__ __launch_bounds__(256) void finalize(
    const float* __restrict__ sq, const float* __restrict__ dws,
    const float* __restrict__ rgb, const float* __restrict__ th,
    float* __restrict__ out)
{
    __shared__ float d[NBLK];        // level-3 region diffs (b*64 + ri*8 + rj)
    __shared__ float d2[BATCH * 16];
    __shared__ float d1[BATCH * 4];
    __shared__ float redbuf[4 * 6];
    const int t = threadIdx.x;

    // density partials (2048 floats as 512 float4)
    float s_sq = 0.f;
    const float4* sq4 = (const float4*)sq;
    #pragma unroll
    for (int k = 0; k < 2; ++k) {
        const float4 v = sq4[t + 256 * k];
        s_sq += (v.x + v.y) + (v.z + v.w);
    }

    // level-3 region diffs: sum 8 chunk partials each
    float l3 = 0.f;
    #pragma unroll
    for (int k = 0; k < 8; ++k) {
        const int r = t + 256 * k;
        const float4* dp = (const float4*)(dws + r * 8);
        const float4 a = dp[0], bb = dp[1];
        const float v = ((a.x + a.y) + (a.z + a.w)) + ((bb.x + bb.y) + (bb.z + bb.w));
        d[r] = v;
        l3 += fabsf(v);
    }
    __syncthreads();

    // level 2: 32 batches x 16 cells, 2x2 aggregation of level-3
    float l2 = 0.f;
    #pragma unroll
    for (int k = 0; k < 2; ++k) {
        const int i = t + 256 * k;
        const int b = i >> 4, r2 = i & 15;
        const int i2 = r2 >> 2, j2 = r2 & 3;
        const float* db = d + b * 64;
        const float v = (db[(2 * i2) * 8 + 2 * j2]     + db[(2 * i2) * 8 + 2 * j2 + 1])
                      + (db[(2 * i2 + 1) * 8 + 2 * j2] + db[(2 * i2 + 1) * 8 + 2 * j2 + 1]);
        d2[i] = v;
        l2 += fabsf(v);
    }
    __syncthreads();

    // level 1: 32 x 4 cells
    float l1 = 0.f;
    if (t < BATCH * 4) {
        const int b = t >> 2, r1 = t & 3;
        const int i1 = r1 >> 1, j1 = r1 & 1;
        const float* db = d2 + b * 16;
        const float v = (db[(2 * i1) * 4 + 2 * j1]     + db[(2 * i1) * 4 + 2 * j1 + 1])
                      + (db[(2 * i1 + 1) * 4 + 2 * j1] + db[(2 * i1 + 1) * 4 + 2 * j1 + 1]);
        d1[t] = v;
        l1 = fabsf(v);
    }
    __syncthreads();

    // per-batch count diff + domain CE
    float cnt = 0.f, dom = 0.f;
    if (t < BATCH) {
        const float c = (d1[t * 4] + d1[t * 4 + 1]) + (d1[t * 4 + 2] + d1[t * 4 + 3]);
        cnt = fabsf(c);
        const float x0 = rgb[t * 2], x1 = rgb[t * 2 + 1];
        const float mx = fmaxf(x0, x1);
        dom  = (mx + logf(expf(x0 - mx) + expf(x1 - mx))) - x0;
        const float y0 = th[t * 2], y1 = th[t * 2 + 1];
        const float my = fmaxf(y0, y1);
        dom += (my + logf(expf(y0 - my) + expf(y1 - my))) - y1;
    }

    // fused 6-value reduction: wave shuffle, then 4-wave LDS combine
    float vals[6] = {s_sq, l3, l2, l1, cnt, dom};
    #pragma unroll
    for (int off = 32; off > 0; off >>= 1) {
        #pragma unroll
        for (int j = 0; j < 6; ++j) vals[j] += __shfl_down(vals[j], off, 64);
    }
    const int wave = t >> 6;
    if ((t & 63) == 0) {
        #pragma unroll
        for (int j = 0; j < 6; ++j) redbuf[wave * 6 + j] = vals[j];
    }
    __syncthreads();
    if (t == 0) {
        float S[6];
        #pragma unroll
        for (int j = 0; j < 6; ++j)
            S[j] = (redbuf[j] + redbuf[6 + j]) + (redbuf[12 + j] + redbuf[18 + j]);
        const float density  = S[0] / (float)((size_t)BATCH * HH * WW);
        const float count_l  = S[4] / (float)BATCH;
        const float regional = ((S[3] + S[2] + S[1]) / (float)BATCH) / 192.0f;
        const float domain   = S[5] / 64.0f;
        out[0] = 100.0f * density + 0.001f * count_l + 1.0f * regional + 0.5f * domain;
    }
}

extern "C" void kernel_launch(void* const* d_in, const int* in_sizes, int n_in,
                              void* d_out, int out_size, void* d_ws, size_t ws_size,
                              hipStream_t stream) {
    const float* pred = (const float*)d_in[0];
    const float* gt   = (const float*)d_in[1];
    const float* rgb  = (const float*)d_in[2];
    const float* th   = (const float*)d_in[3];
    float* out = (float*)d_out;

    float* sq  = (float*)d_ws;         // [2048]
    float* dws = sq + NBLK;            // [2048 * 8] chunk partials

    region_reduce<<<NBLK, 256, 0, stream>>>(pred, gt, sq, dws);
    finalize<<<1, 256, 0, stream>>>(sq, dws, rgb, th, out);
}

// Round 3
// 170.761 us; speedup vs baseline: 1.0484x; 1.0055x over previous
//
#include <hip/hip_runtime.h>
#include <math.h>

// Problem shape (fixed by setup_inputs)
#define BATCH 32
#define HH 768
#define WW 768
#define NBLK 2048   // 32 batches x 8 region-rows x 8 row-chunks

typedef float v4f __attribute__((ext_vector_type(4)));

// ---------------------------------------------------------------------------
// Kernel 1: block = (b, ri, chunk) covering 12 full-width rows.
// 32-lane group g owns column stripe g (96 floats). All 18 float4 loads are
// issued via inline asm (SGPR base + per-lane 32-bit offset) with a single
// s_waitcnt vmcnt(0) afterwards -> 18 loads in flight per thread.
// ---------------------------------------------------------------------------
__global__ __launch_bounds__(256) void region_reduce(
    const float* __restrict__ pred, const float* __restrict__ gt,
    float* __restrict__ sq_out, float* __restrict__ dws)
{
    const int bid   = blockIdx.x;        // b*64 + ri*8 + chunk
    const int b     = bid >> 6;
    const int ri    = (bid >> 3) & 7;
    const int chunk = bid & 7;
    const size_t base = (size_t)b * (HH * WW) + (size_t)(ri * 96 + chunk * 12) * WW;

    const int t = threadIdx.x;
    const int g = t >> 5;       // column stripe 0..7
    const int l = t & 31;

    const float* pb = pred + base;   // block-uniform -> SGPR pair
    const float* gb = gt   + base;

    // stripe = 12 rows x 24 float4; lane l handles q = l + 32k, k=0..8
    unsigned off[9];
    #pragma unroll
    for (int k = 0; k < 9; ++k) {
        const int q   = l + 32 * k;          // 0..287
        const int row = q / 24;
        const int c   = q - row * 24;
        off[k] = (unsigned)((g * 96 + row * WW + c * 4) * sizeof(float));
    }

    v4f p[9], q4[9];
    #pragma unroll
    for (int k = 0; k < 9; ++k)
        asm volatile("global_load_dwordx4 %0, %1, %2"
                     : "=&v"(p[k]) : "v"(off[k]), "s"(pb));
    #pragma unroll
    for (int k = 0; k < 9; ++k)
        asm volatile("global_load_dwordx4 %0, %1, %2"
                     : "=&v"(q4[k]) : "v"(off[k]), "s"(gb));
    // One wait for all 18; "+v" ties force every use to stay after it.
    asm volatile("s_waitcnt vmcnt(0)"
                 : "+v"(p[0]), "+v"(p[1]), "+v"(p[2]), "+v"(p[3]), "+v"(p[4]),
                   "+v"(p[5]), "+v"(p[6]), "+v"(p[7]), "+v"(p[8]),
                   "+v"(q4[0]), "+v"(q4[1]), "+v"(q4[2]), "+v"(q4[3]), "+v"(q4[4]),
                   "+v"(q4[5]), "+v"(q4[6]), "+v"(q4[7]), "+v"(q4[8])
                 :: "memory");

    float sq = 0.f, ds = 0.f;
    #pragma unroll
    for (int k = 0; k < 9; ++k) {
        const float dx = p[k][0] - q4[k][0];
        const float dy = p[k][1] - q4[k][1];
        const float dz = p[k][2] - q4[k][2];
        const float dw = p[k][3] - q4[k][3];
        sq += (dx * dx + dy * dy) + (dz * dz + dw * dw);
        ds += (dx + dy) + (dz + dw);
    }

    // ds: reduce within the 32-lane group (stripe-local)
    #pragma unroll
    for (int off_ = 16; off_ > 0; off_ >>= 1) ds += __shfl_down(ds, off_, 64);
    // sq: reduce across the full 64-lane wave
    #pragma unroll
    for (int off_ = 32; off_ > 0; off_ >>= 1) sq += __shfl_down(sq, off_, 64);

    if (l == 0) dws[((((b << 3) + ri) << 3) + g) * 8 + chunk] = ds;

    __shared__ float lsq[4];
    const int wave = t >> 6;
    if ((t & 63) == 0) lsq[wave] = sq;
    __syncthreads();
    if (t == 0) sq_out[bid] = (lsq[0] + lsq[1]) + (lsq[2] + lsq[3]);
}

// ---------------------------------------------------------------------------
// Kernel 2: single block. Aggregates chunk partials -> level-3 regions,
// builds levels 2/1, count loss, domain CE, final weighted sum.
// ---------------------------------------------------------------------------
__global__ __launch_bounds__(256) void finalize(
    const float* __restrict__ sq, const float* __restrict__ dws,
    const float* __restrict__ rgb, const float* __restrict__ th,
    float* __restrict__ out)
{
    __shared__ float d[NBLK];        // level-3 region diffs (b*64 + ri*8 + rj)
    __shared__ float d2[BATCH * 16];
    __shared__ float d1[BATCH * 4];
    __shared__ float redbuf[4 * 6];
    const int t = threadIdx.x;

    // density partials (2048 floats as 512 float4)
    float s_sq = 0.f;
    const float4* sq4 = (const float4*)sq;
    #pragma unroll
    for (int k = 0; k < 2; ++k) {
        const float4 v = sq4[t + 256 * k];
        s_sq += (v.x + v.y) + (v.z + v.w);
    }

    // level-3 region diffs: sum 8 chunk partials each
    float l3 = 0.f;
    #pragma unroll
    for (int k = 0; k < 8; ++k) {
        const int r = t + 256 * k;
        const float4* dp = (const float4*)(dws + r * 8);
        const float4 a = dp[0], bb = dp[1];
        const float v = ((a.x + a.y) + (a.z + a.w)) + ((bb.x + bb.y) + (bb.z + bb.w));
        d[r] = v;
        l3 += fabsf(v);
    }
    __syncthreads();

    // level 2: 32 batches x 16 cells, 2x2 aggregation of level-3
    float l2 = 0.f;
    #pragma unroll
    for (int k = 0; k < 2; ++k) {
        const int i = t + 256 * k;
        const int b = i >> 4, r2 = i & 15;
        const int i2 = r2 >> 2, j2 = r2 & 3;
        const float* db = d + b * 64;
        const float v = (db[(2 * i2) * 8 + 2 * j2]     + db[(2 * i2) * 8 + 2 * j2 + 1])
                      + (db[(2 * i2 + 1) * 8 + 2 * j2] + db[(2 * i2 + 1) * 8 + 2 * j2 + 1]);
        d2[i] = v;
        l2 += fabsf(v);
    }
    __syncthreads();

    // level 1: 32 x 4 cells
    float l1 = 0.f;
    if (t < BATCH * 4) {
        const int b = t >> 2, r1 = t & 3;
        const int i1 = r1 >> 1, j1 = r1 & 1;
        const float* db = d2 + b * 16;
        const float v = (db[(2 * i1) * 4 + 2 * j1]     + db[(2 * i1) * 4 + 2 * j1 + 1])
                      + (db[(2 * i1 + 1) * 4 + 2 * j1] + db[(2 * i1 + 1) * 4 + 2 * j1 + 1]);
        d1[t] = v;
        l1 = fabsf(v);
    }
    __syncthreads();

    // per-batch count diff + domain CE
    float cnt = 0.f, dom = 0.f;
    if (t < BATCH) {
        const float c = (d1[t * 4] + d1[t * 4 + 1]) + (d1[t * 4 + 2] + d1[t * 4 + 3]);
        cnt = fabsf(c);
        const float x0 = rgb[t * 2], x1 = rgb[t * 2 + 1];
        const float mx = fmaxf(x0, x1);
        dom  = (mx + logf(expf(x0 - mx) + expf(x1 - mx))) - x0;
        const float y0 = th[t * 2], y1 = th[t * 2 + 1];
        const float my = fmaxf(y0, y1);
        dom += (my + logf(expf(y0 - my) + expf(y1 - my))) - y1;
    }

    // fused 6-value reduction: wave shuffle, then 4-wave LDS combine
    float vals[6] = {s_sq, l3, l2, l1, cnt, dom};
    #pragma unroll
    for (int off = 32; off > 0; off >>= 1) {
        #pragma unroll
        for (int j = 0; j < 6; ++j) vals[j] += __shfl_down(vals[j], off, 64);
    }
    const int wave = t >> 6;
    if ((t & 63) == 0) {
        #pragma unroll
        for (int j = 0; j < 6; ++j) redbuf[wave * 6 + j] = vals[j];
    }
    __syncthreads();
    if (t == 0) {
        float S[6];
        #pragma unroll
        for (int j = 0; j < 6; ++j)
            S[j] = (redbuf[j] + redbuf[6 + j]) + (redbuf[12 + j] + redbuf[18 + j]);
        const float density  = S[0] / (float)((size_t)BATCH * HH * WW);
        const float count_l  = S[4] / (float)BATCH;
        const float regional = ((S[3] + S[2] + S[1]) / (float)BATCH) / 192.0f;
        const float domain   = S[5] / 64.0f;
        out[0] = 100.0f * density + 0.001f * count_l + 1.0f * regional + 0.5f * domain;
    }
}

extern "C" void kernel_launch(void* const* d_in, const int* in_sizes, int n_in,
                              void* d_out, int out_size, void* d_ws, size_t ws_size,
                              hipStream_t stream) {
    const float* pred = (const float*)d_in[0];
    const float* gt   = (const float*)d_in[1];
    const float* rgb  = (const float*)d_in[2];
    const float* th   = (const float*)d_in[3];
    float* out = (float*)d_out;

    float* sq  = (float*)d_ws;         // [2048]
    float* dws = sq + NBLK;            // [2048 * 8] chunk partials

    region_reduce<<<NBLK, 256, 0, stream>>>(pred, gt, sq, dws);
    finalize<<<1, 256, 0, stream>>>(sq, dws, rgb, th, out);
}